// Round 7
// baseline (41827.347 us; speedup 1.0000x reference)
//
#include <hip/hip_runtime.h>
#include <stdint.h>
#include <stddef.h>

#define Bq 128
#define Tq 512
#define Vq 32000
#define Dq 1024
#define Hq 2048
#define BH (Bq * Hq)

typedef __attribute__((ext_vector_type(8))) _Float16 h8;   // 8 x fp16
typedef __attribute__((ext_vector_type(4))) float f4;
typedef unsigned long long ull;

__device__ __forceinline__ float h2f(unsigned short u){
  _Float16 h; __builtin_memcpy(&h, &u, 2); return (float)h;
}
__device__ __forceinline__ unsigned short f2h(float f){
  _Float16 h = (_Float16)f; unsigned short u; __builtin_memcpy(&u, &h, 2); return u;
}
__device__ __forceinline__ float fast_tanh(float x){
  float e = __expf(2.0f * x);
  return 1.0f - 2.0f / (e + 1.0f);
}

// ---- the ONLY cross-block primitives: agent-scope atomics (proven rounds 2/3) ----
__device__ __forceinline__ void st_h(unsigned short* p, unsigned short v){
  __hip_atomic_store(p, v, __ATOMIC_RELAXED, __HIP_MEMORY_SCOPE_AGENT);
}
__device__ __forceinline__ unsigned short ld_h(const unsigned short* p){
  return __hip_atomic_load(p, __ATOMIC_RELAXED, __HIP_MEMORY_SCOPE_AGENT);
}
__device__ __forceinline__ ull ld_q(const ull* p){
  return __hip_atomic_load(p, __ATOMIC_RELAXED, __HIP_MEMORY_SCOPE_AGENT);
}
__device__ __forceinline__ unsigned ld_u(const unsigned* p){
  return __hip_atomic_load(p, __ATOMIC_RELAXED, __HIP_MEMORY_SCOPE_AGENT);
}
__device__ __forceinline__ unsigned add_rel(unsigned* p, unsigned v){
  return __hip_atomic_fetch_add(p, v, __ATOMIC_RELEASE, __HIP_MEMORY_SCOPE_AGENT);
}

// ---------------- preprocessing ----------------

// in[K][N] f32 -> out[N][K] fp16
__global__ void transpose_cast(const float* __restrict__ in, unsigned short* __restrict__ out, int K, int N){
  __shared__ float tile[32][33];
  int n0 = blockIdx.x * 32, k0 = blockIdx.y * 32;
  int tx = threadIdx.x, ty = threadIdx.y;
  #pragma unroll
  for (int i = 0; i < 32; i += 8)
    tile[ty + i][tx] = in[(size_t)(k0 + ty + i) * N + n0 + tx];
  __syncthreads();
  #pragma unroll
  for (int i = 0; i < 32; i += 8)
    out[(size_t)(n0 + ty + i) * K + k0 + tx] = f2h(tile[tx][ty + i]);
}

__global__ void h2f_out(const unsigned short* __restrict__ in, float* __restrict__ out, int n){
  int i = blockIdx.x * blockDim.x + threadIdx.x;
  if (i < n) out[i] = h2f(in[i]);
}

// ---------------- inner GEMM: acc[MT][NT] += A x B(LDS swizzled) ----------------
// MODE 1: A via 8B agent-atomic loads (cross-XCD mutable h panels)
// MODE 2: A via plain f32 loads + in-register fp16 convert (read-only emb)
// Software-pipelined 4 deep; compiler schedules waitcnts.

template<int MT, int NT, int KF, int MODE>
__device__ __forceinline__ void mmX(f4 (&acc)[MT][NT],
    const char* const (&ap)[MT], const char* Wl,
    const int (&bb)[NT], const int (&swz)[NT])
{
  h8 ab[4][MT];
  auto lda = [&](int kf, int mt) -> h8 {
    if constexpr (MODE == 1){
      const ull* p = (const ull*)(ap[mt] + kf * 64);
      ull lo = ld_q(p);
      ull hi = ld_q(p + 1);
      union { ull v[2]; h8 h; } u; u.v[0] = lo; u.v[1] = hi; return u.h;
    } else {
      const float4* p = (const float4*)(ap[mt] + kf * 128);
      float4 x = p[0], y = p[1];
      h8 h;
      h[0] = (_Float16)x.x; h[1] = (_Float16)x.y; h[2] = (_Float16)x.z; h[3] = (_Float16)x.w;
      h[4] = (_Float16)y.x; h[5] = (_Float16)y.y; h[6] = (_Float16)y.z; h[7] = (_Float16)y.w;
      return h;
    }
  };
  #pragma unroll
  for (int kf = 0; kf < 4 && kf < KF; ++kf)
    #pragma unroll
    for (int mt = 0; mt < MT; ++mt)
      ab[kf][mt] = lda(kf, mt);

  #pragma unroll
  for (int kf = 0; kf < KF; ++kf){
    h8 b[NT];
    #pragma unroll
    for (int nt = 0; nt < NT; ++nt)
      b[nt] = *(const h8*)(Wl + ((bb[nt] + kf * 64) ^ swz[nt]));
    #pragma unroll
    for (int mt = 0; mt < MT; ++mt)
      #pragma unroll
      for (int nt = 0; nt < NT; ++nt)
        acc[mt][nt] = __builtin_amdgcn_mfma_f32_16x16x32_f16(ab[kf & 3][mt], b[nt], acc[mt][nt], 0, 0, 0);
    if (kf + 4 < KF){
      #pragma unroll
      for (int mt = 0; mt < MT; ++mt)
        ab[(kf + 4) & 3][mt] = lda(kf + 4, mt);
    }
  }
}

// ---------------- grid barrier: release arrive, relaxed spin, NO fences ----------------
// Data is already L3-visible (atomic stores); release arrive orders them (proven r3).

__device__ __forceinline__ void gbar(unsigned* arr, unsigned* gc, int sub, int it){
  __syncthreads();                               // all waves' stores vmcnt-drained
  if (threadIdx.x == 0){
    add_rel(arr, 1u);
    if (sub == 0){
      while (ld_u(arr) < 32u * (unsigned)(it + 1)) __builtin_amdgcn_s_sleep(1);
      add_rel(gc, 1u);
    }
    while (ld_u(gc) < 8u * (unsigned)(it + 1)) __builtin_amdgcn_s_sleep(1);
    asm volatile("" ::: "memory");
  }
  __syncthreads();
}

// ---------------- 4-role persistent pipeline (placement-independent) ----------------
// grp = bid>>5: g0=ih0(32) g1,2=hh0(64) g3,4=ih1(64) g5,6=hh1(64) g7=idle(32)
// iter i: G0: P0_i = emb[tok_i]@Wih0+b0 ; G1: h0_{i-1} = tanh(P0 + h0_{i-2}@Whh0)
//         G2: P1_{i-2} = h0_{i-2}@Wih1+b1 ; G3: h1_{i-3} = tanh(P1 + h1_{i-4}@Whh1)
// ALL cross-block h/P bytes: atomic store -> L3 -> atomic load. No cache games.

__global__ __launch_bounds__(512, 2) void rnn4(
    const float* __restrict__ emb,      // [V][1024] f32 (read-only: plain loads)
    const int* __restrict__ tokens,     // [B][T] int32 or int64 (sniffed)
    const unsigned short* __restrict__ Wih0T,  // [2048][1024] fp16
    const unsigned short* __restrict__ Whh0T,  // [2048][2048]
    const unsigned short* __restrict__ Wih1T,  // [2048][2048]
    const unsigned short* __restrict__ Whh1T,  // [2048][2048]
    const float* __restrict__ b0,
    const float* __restrict__ b1,
    unsigned short* __restrict__ h0,    // [2][BH] zeroed
    unsigned short* __restrict__ h1,    // [2][BH] zeroed
    unsigned short* __restrict__ P0,    // [2][BH]
    unsigned short* __restrict__ P1a,   // [2][BH]
    unsigned short* __restrict__ P1b,   // [2][BH]
    const int* __restrict__ lengths,
    unsigned* __restrict__ zp)          // zeroed control page
{
  extern __shared__ char lds[];
  char* Wl = lds;
  char* zone = lds + 131072;

  const int bid = blockIdx.x;
  const int grp = bid >> 5, sub = bid & 31;
  const int tid = threadIdx.x, l = tid & 63, w = tid >> 6;
  const int mw = w & 1, kw = w >> 1;          // 2 M-halves x 4 K-slices
  const int fr = l & 15, q = l >> 4;

  unsigned* gc  = zp;
  unsigned* arr = zp + 64 + grp * 64;

  int role = -1, tile = 0;
  if (grp == 0){ role = 0; tile = sub; }
  else if (grp <= 2){ role = 1; tile = (grp - 1) * 32 + sub; }
  else if (grp <= 4){ role = 2; tile = (grp - 3) * 32 + sub; }
  else if (grp <= 6){ role = 3; tile = (grp - 5) * 32 + sub; }

  const bool ihrole = (role == 0 || role == 2);
  const int kh = (role == 2) ? (tile & 1) : 0;
  const int c0 = (role == 0) ? tile * 64 : (role == 2) ? (tile >> 1) * 64 : tile * 32;

  // ---- fill W slice into swizzled LDS (once; read-only inputs, plain loads) ----
  if (role >= 0){
    const unsigned short* src; int NC, KC, srcK, kofs;
    if (role == 0){ src = Wih0T; NC = 64; KC = 1024; srcK = 1024; kofs = 0; }
    else if (role == 2){ src = Wih1T; NC = 64; KC = 1024; srcK = 2048; kofs = kh * 1024; }
    else { src = (role == 1) ? Whh0T : Whh1T; NC = 32; KC = 2048; srcK = 2048; kofs = 0; }
    int nch = NC * (KC / 8);
    for (int i2 = tid; i2 < nch; i2 += 512){
      int c = i2 / (KC / 8), kg = i2 % (KC / 8);
      uint4 v = *(const uint4*)(src + (size_t)(c0 + c) * srcK + kofs + kg * 8);
      int byte = (c * KC + kg * 8) * 2 ^ ((c & 31) << 4);
      *(uint4*)(Wl + byte) = v;
    }
  }
  __syncthreads();

  bool w64 = false;
  if (grp == 0) w64 = ((tokens[1] | tokens[3] | tokens[5] | tokens[7]) == 0);

  int lenr[4][4];
  if (role == 1 || role == 3){
    #pragma unroll
    for (int mt = 0; mt < 4; ++mt)
      #pragma unroll
      for (int r = 0; r < 4; ++r)
        lenr[mt][r] = lengths[mw * 64 + mt * 16 + q * 4 + r];
  }
  float biasv[4] = {0.f, 0.f, 0.f, 0.f};
  if (role == 0){
    #pragma unroll
    for (int nt = 0; nt < 4; ++nt) biasv[nt] = b0[c0 + nt * 16 + fr];
  } else if (role == 2 && kh == 0){
    #pragma unroll
    for (int nt = 0; nt < 4; ++nt) biasv[nt] = b1[c0 + nt * 16 + fr];
  }
  float hp[4][2][4];                      // register-carried h_prev (hh roles, kw==0)
  #pragma unroll
  for (int a = 0; a < 4; ++a)
    #pragma unroll
    for (int b = 0; b < 2; ++b)
      #pragma unroll
      for (int c = 0; c < 4; ++c) hp[a][b][c] = 0.f;

  for (int it = 0; it < 515; ++it){
    if (role == 0){
      // ======== ih0: A = emb rows (plain f32 + cvt), MT=4 NT=4 KF=8 ========
      const int t = it;
      if (t <= 511){
        const int KC = 1024;
        int bb[4], swz[4];
        #pragma unroll
        for (int nt = 0; nt < 4; ++nt){
          int cl = nt * 16 + fr;
          bb[nt] = (cl * KC + kw * 256 + q * 8) * 2;
          swz[nt] = (cl & 31) << 4;
        }
        const char* ap[4];
        #pragma unroll
        for (int mt = 0; mt < 4; ++mt){
          int row = mw * 64 + mt * 16 + fr;
          long idx = (long)row * Tq + t;
          int tok = w64 ? tokens[2 * idx] : tokens[idx];
          ap[mt] = (const char*)(emb + (size_t)tok * Dq) + kw * 1024 + q * 32;  // f32 bytes
        }
        f4 acc[4][4] = {};
        mmX<4, 4, 8, 2>(acc, ap, Wl, bb, swz);

        unsigned short* dst = P0 + (t & 1) * BH;
        #pragma unroll
        for (int mwr = 0; mwr < 2; ++mwr){
          __syncthreads();
          if (mw == mwr && kw > 0){
            #pragma unroll
            for (int mt = 0; mt < 4; ++mt)
              #pragma unroll
              for (int nt = 0; nt < 4; ++nt){
                ushort4 u = { f2h(acc[mt][nt][0]), f2h(acc[mt][nt][1]),
                              f2h(acc[mt][nt][2]), f2h(acc[mt][nt][3]) };
                *(ushort4*)(zone + (kw - 1) * 8192 + (mt * 4 + nt) * 512 + l * 8) = u;
              }
          }
          __syncthreads();
          if (mw == mwr && kw == 0){
            #pragma unroll
            for (int mt = 0; mt < 4; ++mt)
              #pragma unroll
              for (int nt = 0; nt < 4; ++nt){
                f4 s = acc[mt][nt];
                #pragma unroll
                for (int j = 0; j < 3; ++j){
                  ushort4 u = *(ushort4*)(zone + j * 8192 + (mt * 4 + nt) * 512 + l * 8);
                  s[0] += h2f(u.x); s[1] += h2f(u.y); s[2] += h2f(u.z); s[3] += h2f(u.w);
                }
                int col = c0 + nt * 16 + fr;
                #pragma unroll
                for (int r = 0; r < 4; ++r){
                  int row = mw * 64 + mt * 16 + q * 4 + r;
                  st_h(&dst[(size_t)row * Hq + col], f2h(s[r] + biasv[nt]));
                }
              }
          }
        }
      }
    } else if (role == 2){
      // ======== ih1: A = h0_{it-2} via atomics, MT=4 NT=4 KF=8, K-half kh ========
      const int t = it - 2;
      if (t >= 0 && t <= 511){
        const int KC = 1024;
        int bb[4], swz[4];
        #pragma unroll
        for (int nt = 0; nt < 4; ++nt){
          int cl = nt * 16 + fr;
          bb[nt] = (cl * KC + kw * 256 + q * 8) * 2;
          swz[nt] = (cl & 31) << 4;
        }
        const unsigned short* hsrc = h0 + (it & 1) * BH;   // h0_{it-2}
        const char* ap[4];
        #pragma unroll
        for (int mt = 0; mt < 4; ++mt){
          int row = mw * 64 + mt * 16 + fr;
          ap[mt] = (const char*)(hsrc + (size_t)row * Hq + kh * 1024 + kw * 256 + q * 8);
        }
        f4 acc[4][4] = {};
        mmX<4, 4, 8, 1>(acc, ap, Wl, bb, swz);

        unsigned short* dst = (kh == 0 ? P1a : P1b) + (t & 1) * BH;
        #pragma unroll
        for (int mwr = 0; mwr < 2; ++mwr){
          __syncthreads();
          if (mw == mwr && kw > 0){
            #pragma unroll
            for (int mt = 0; mt < 4; ++mt)
              #pragma unroll
              for (int nt = 0; nt < 4; ++nt){
                ushort4 u = { f2h(acc[mt][nt][0]), f2h(acc[mt][nt][1]),
                              f2h(acc[mt][nt][2]), f2h(acc[mt][nt][3]) };
                *(ushort4*)(zone + (kw - 1) * 8192 + (mt * 4 + nt) * 512 + l * 8) = u;
              }
          }
          __syncthreads();
          if (mw == mwr && kw == 0){
            #pragma unroll
            for (int mt = 0; mt < 4; ++mt)
              #pragma unroll
              for (int nt = 0; nt < 4; ++nt){
                f4 s = acc[mt][nt];
                #pragma unroll
                for (int j = 0; j < 3; ++j){
                  ushort4 u = *(ushort4*)(zone + j * 8192 + (mt * 4 + nt) * 512 + l * 8);
                  s[0] += h2f(u.x); s[1] += h2f(u.y); s[2] += h2f(u.z); s[3] += h2f(u.w);
                }
                int col = c0 + nt * 16 + fr;
                #pragma unroll
                for (int r = 0; r < 4; ++r){
                  int row = mw * 64 + mt * 16 + q * 4 + r;
                  st_h(&dst[(size_t)row * Hq + col], f2h(s[r] + biasv[nt]));
                }
              }
          }
        }
      }
    } else if (role == 1 || role == 3){
      // ======== hh: A = h_{t-1} via atomics, MT=4 NT=2 KF=16 ========
      const int t = (role == 1) ? it - 1 : it - 3;
      if (t >= 0 && t <= 511){
        const int KC = 2048;
        int bb[2], swz[2];
        #pragma unroll
        for (int nt = 0; nt < 2; ++nt){
          int cl = nt * 16 + fr;
          bb[nt] = (cl * KC + kw * 512 + q * 8) * 2;
          swz[nt] = (cl & 31) << 4;
        }
        unsigned short* hbuf = (role == 1) ? h0 : h1;
        const unsigned short* hsrc = hbuf + (it & 1) * BH;   // h_{t-1}
        const char* ap[4];
        #pragma unroll
        for (int mt = 0; mt < 4; ++mt){
          int row = mw * 64 + mt * 16 + fr;
          ap[mt] = (const char*)(hsrc + (size_t)row * Hq + kw * 512 + q * 8);
        }
        f4 acc[4][2] = {};
        mmX<4, 2, 16, 1>(acc, ap, Wl, bb, swz);

        const unsigned short* Pa = ((role == 1) ? P0 : P1a) + (t & 1) * BH;
        const unsigned short* Pb = (role == 3) ? (P1b + (t & 1) * BH) : nullptr;
        unsigned short* hdst = hbuf + (t & 1) * BH;
        #pragma unroll
        for (int mwr = 0; mwr < 2; ++mwr){
          __syncthreads();
          if (mw == mwr && kw > 0){
            #pragma unroll
            for (int mt = 0; mt < 4; ++mt)
              #pragma unroll
              for (int nt = 0; nt < 2; ++nt){
                ushort4 u = { f2h(acc[mt][nt][0]), f2h(acc[mt][nt][1]),
                              f2h(acc[mt][nt][2]), f2h(acc[mt][nt][3]) };
                *(ushort4*)(zone + (kw - 1) * 8192 + (mt * 2 + nt) * 512 + l * 8) = u;
              }
          }
          __syncthreads();
          if (mw == mwr && kw == 0){
            #pragma unroll
            for (int mt = 0; mt < 4; ++mt)
              #pragma unroll
              for (int nt = 0; nt < 2; ++nt){
                f4 s = acc[mt][nt];
                #pragma unroll
                for (int j = 0; j < 3; ++j){
                  ushort4 u = *(ushort4*)(zone + j * 8192 + (mt * 2 + nt) * 512 + l * 8);
                  s[0] += h2f(u.x); s[1] += h2f(u.y); s[2] += h2f(u.z); s[3] += h2f(u.w);
                }
                int col = c0 + nt * 16 + fr;
                #pragma unroll
                for (int r = 0; r < 4; ++r){
                  int row = mw * 64 + mt * 16 + q * 4 + r;
                  size_t o = (size_t)row * Hq + col;
                  float v = s[r] + h2f(ld_h(&Pa[o]));
                  if (role == 3) v += h2f(ld_h(&Pb[o]));
                  float hn = fast_tanh(v);
                  float ho = (t < lenr[mt][r]) ? hn : hp[mt][nt][r];
                  hp[mt][nt][r] = ho;
                  st_h(&hdst[o], f2h(ho));
                }
              }
          }
        }
      }
    }
    if (it < 514) gbar(arr, gc, sub, it);
  }
}

// ---------------- launch ----------------

extern "C" void kernel_launch(void* const* d_in, const int* in_sizes, int n_in,
                              void* d_out, int out_size, void* d_ws, size_t ws_size,
                              hipStream_t stream)
{
  (void)in_sizes; (void)n_in; (void)out_size; (void)ws_size;
  const int*   tokens  = (const int*)d_in[0];
  const int*   lengths = (const int*)d_in[1];
  const float* emb     = (const float*)d_in[2];
  const float* Wih0    = (const float*)d_in[3];
  const float* Whh0    = (const float*)d_in[4];
  const float* b0      = (const float*)d_in[5];
  const float* Wih1    = (const float*)d_in[6];
  const float* Whh1    = (const float*)d_in[7];
  const float* b1      = (const float*)d_in[8];

  char* ws = (char*)d_ws;
  size_t off = 0;
  auto alloc = [&](size_t bytes)->char*{
    char* p = ws + off; off += (bytes + 255) & ~(size_t)255; return p;
  };
  unsigned short* WTih0 = (unsigned short*)alloc((size_t)Hq * Dq * 2);   //  4 MB
  unsigned short* WThh0 = (unsigned short*)alloc((size_t)Hq * Hq * 2);   //  8 MB
  unsigned short* WTih1 = (unsigned short*)alloc((size_t)Hq * Hq * 2);   //  8 MB
  unsigned short* WThh1 = (unsigned short*)alloc((size_t)Hq * Hq * 2);   //  8 MB
  unsigned short* h0b   = (unsigned short*)alloc((size_t)2 * BH * 2);    //  1 MB
  unsigned short* h1b   = (unsigned short*)alloc((size_t)2 * BH * 2);
  unsigned short* P0b   = (unsigned short*)alloc((size_t)2 * BH * 2);
  unsigned short* P1ab  = (unsigned short*)alloc((size_t)2 * BH * 2);
  unsigned short* P1bb  = (unsigned short*)alloc((size_t)2 * BH * 2);
  unsigned*       zp    = (unsigned*)alloc(4096);
  // total ~34 MB

  transpose_cast<<<dim3(Hq / 32, Dq / 32), dim3(32, 8), 0, stream>>>(Wih0, WTih0, Dq, Hq);
  transpose_cast<<<dim3(Hq / 32, Hq / 32), dim3(32, 8), 0, stream>>>(Whh0, WThh0, Hq, Hq);
  transpose_cast<<<dim3(Hq / 32, Hq / 32), dim3(32, 8), 0, stream>>>(Wih1, WTih1, Hq, Hq);
  transpose_cast<<<dim3(Hq / 32, Hq / 32), dim3(32, 8), 0, stream>>>(Whh1, WThh1, Hq, Hq);

  hipMemsetAsync(h0b, 0, (size_t)2 * BH * 2, stream);
  hipMemsetAsync(h1b, 0, (size_t)2 * BH * 2, stream);
  hipMemsetAsync(zp, 0, 4096, stream);

  hipFuncSetAttribute((const void*)rnn4, hipFuncAttributeMaxDynamicSharedMemorySize, 155648);
  rnn4<<<256, 512, 155648, stream>>>(emb, tokens, WTih0, WThh0, WTih1, WThh1,
                                     b0, b1, h0b, h1b, P0b, P1ab, P1bb,
                                     lengths, zp);

  h2f_out<<<(BH + 255) / 256, 256, 0, stream>>>(h1b + BH, (float*)d_out, BH);
}

// Round 9
// 35881.644 us; speedup vs baseline: 1.1657x; 1.1657x over previous
//
#include <hip/hip_runtime.h>
#include <stdint.h>
#include <stddef.h>

#define Bq 128
#define Tq 512
#define Vq 32000
#define Dq 1024
#define Hq 2048
#define BH (Bq * Hq)

typedef __attribute__((ext_vector_type(8))) _Float16 h8;   // 8 x fp16
typedef __attribute__((ext_vector_type(4))) float f4;
typedef unsigned long long ull;

__device__ __forceinline__ float h2f(unsigned short u){
  _Float16 h; __builtin_memcpy(&h, &u, 2); return (float)h;
}
__device__ __forceinline__ unsigned short f2h(float f){
  _Float16 h = (_Float16)f; unsigned short u; __builtin_memcpy(&u, &h, 2); return u;
}
__device__ __forceinline__ float fast_tanh(float x){
  float e = __expf(2.0f * x);
  return 1.0f - 2.0f / (e + 1.0f);
}

// ---- cross-block primitives (proven r7): agent-scope atomics ----
__device__ __forceinline__ void st_h(unsigned short* p, unsigned short v){
  __hip_atomic_store(p, v, __ATOMIC_RELAXED, __HIP_MEMORY_SCOPE_AGENT);
}
__device__ __forceinline__ unsigned short ld_h(const unsigned short* p){
  return __hip_atomic_load(p, __ATOMIC_RELAXED, __HIP_MEMORY_SCOPE_AGENT);
}
__device__ __forceinline__ unsigned ld_u(const unsigned* p){
  return __hip_atomic_load(p, __ATOMIC_RELAXED, __HIP_MEMORY_SCOPE_AGENT);
}
__device__ __forceinline__ unsigned add_rel(unsigned* p, unsigned v){
  return __hip_atomic_fetch_add(p, v, __ATOMIC_RELEASE, __HIP_MEMORY_SCOPE_AGENT);
}

// 16B load, L2-bypass (sc1) -> reads IF; coherent with agent-atomic stores.
// 4x fewer IF ops than 2x8B atomic loads. (Assembles+launches: verified r8.)
__device__ __forceinline__ h8 ald16(const void* p){
  h8 d;
  asm volatile("global_load_dwordx4 %0, %1, off sc1" : "=v"(d) : "v"(p));
  return d;
}
template<int N>
__device__ __forceinline__ void vwait(){
  asm volatile("s_waitcnt vmcnt(%0)" :: "i"(N) : "memory");
  __builtin_amdgcn_sched_barrier(0);   // rule #18: pin consumers below the wait
}

// ---------------- preprocessing ----------------

// in[K][N] f32 -> out[N][K] fp16
__global__ void transpose_cast(const float* __restrict__ in, unsigned short* __restrict__ out, int K, int N){
  __shared__ float tile[32][33];
  int n0 = blockIdx.x * 32, k0 = blockIdx.y * 32;
  int tx = threadIdx.x, ty = threadIdx.y;
  #pragma unroll
  for (int i = 0; i < 32; i += 8)
    tile[ty + i][tx] = in[(size_t)(k0 + ty + i) * N + n0 + tx];
  __syncthreads();
  #pragma unroll
  for (int i = 0; i < 32; i += 8)
    out[(size_t)(n0 + ty + i) * K + k0 + tx] = f2h(tile[tx][ty + i]);
}

__global__ void h2f_out(const unsigned short* __restrict__ in, float* __restrict__ out, int n){
  int i = blockIdx.x * blockDim.x + threadIdx.x;
  if (i < n) out[i] = h2f(in[i]);
}

// ---------------- inner GEMM: acc[MT][NT] += A x B(LDS swizzled) ----------------
// MODE 1: A via 16B sc1 asm loads. 4 batches of MT in flight; manual
//   vmcnt(3MT/2MT/MT/0) ladder; batch kf+4 issued into slot kf&3 AFTER the
//   kf MFMAs consume it (r8's bug was issuing BEFORE consumption: the new
//   in-flight load's dest regs were read by MFMA -> garbage/fault).
// MODE 2: A via plain f32 loads + in-register fp16 convert (read-only emb;
//   compiler-managed waitcnts).

template<int MT, int NT, int KF, int MODE>
__device__ __forceinline__ void mmX(f4 (&acc)[MT][NT],
    const char* const (&ap)[MT], const char* Wl,
    const int (&bb)[NT], const int (&swz)[NT])
{
  h8 ab[4][MT];
  auto lda2 = [&](int kf, int mt) -> h8 {   // MODE 2 only
    const float4* p = (const float4*)(ap[mt] + kf * 128);
    float4 x = p[0], y = p[1];
    h8 h;
    h[0] = (_Float16)x.x; h[1] = (_Float16)x.y; h[2] = (_Float16)x.z; h[3] = (_Float16)x.w;
    h[4] = (_Float16)y.x; h[5] = (_Float16)y.y; h[6] = (_Float16)y.z; h[7] = (_Float16)y.w;
    return h;
  };

  #pragma unroll
  for (int kf = 0; kf < 4 && kf < KF; ++kf)
    #pragma unroll
    for (int mt = 0; mt < MT; ++mt){
      if constexpr (MODE == 1) ab[kf][mt] = ald16(ap[mt] + kf * 64);
      else                     ab[kf][mt] = lda2(kf, mt);
    }

  #pragma unroll
  for (int kf = 0; kf < KF; ++kf){
    if constexpr (MODE == 1){
      const int rem = KF - 1 - kf;
      if (rem >= 3) vwait<3*MT>();
      else if (rem == 2) vwait<2*MT>();
      else if (rem == 1) vwait<MT>();
      else vwait<0>();
    }
    h8 b[NT];
    #pragma unroll
    for (int nt = 0; nt < NT; ++nt)
      b[nt] = *(const h8*)(Wl + ((bb[nt] + kf * 64) ^ swz[nt]));
    #pragma unroll
    for (int mt = 0; mt < MT; ++mt)
      #pragma unroll
      for (int nt = 0; nt < NT; ++nt)
        acc[mt][nt] = __builtin_amdgcn_mfma_f32_16x16x32_f16(ab[kf & 3][mt], b[nt], acc[mt][nt], 0, 0, 0);
    if (kf + 4 < KF){                       // issue AFTER consumption (r7 order)
      #pragma unroll
      for (int mt = 0; mt < MT; ++mt){
        if constexpr (MODE == 1) ab[kf & 3][mt] = ald16(ap[mt] + (kf + 4) * 64);
        else                     ab[kf & 3][mt] = lda2(kf + 4, mt);
      }
    }
  }
}

// ---------------- grid barrier: release arrive, relaxed spin (proven r7) ----------------

__device__ __forceinline__ void gbar(unsigned* arr, unsigned* gc, int sub, int it){
  __syncthreads();                               // all waves' stores vmcnt-drained
  if (threadIdx.x == 0){
    add_rel(arr, 1u);
    if (sub == 0){
      while (ld_u(arr) < 32u * (unsigned)(it + 1)) __builtin_amdgcn_s_sleep(1);
      add_rel(gc, 1u);
    }
    while (ld_u(gc) < 8u * (unsigned)(it + 1)) __builtin_amdgcn_s_sleep(1);
    asm volatile("" ::: "memory");
  }
  __syncthreads();
}

// ---------------- 4-role persistent pipeline (placement-independent) ----------------
// grp = bid>>5: g0=ih0(32) g1,2=hh0(64) g3,4=ih1(64) g5,6=hh1(64) g7=idle(32)
// iter i: G0: P0_i = emb[tok_i]@Wih0+b0 ; G1: h0_{i-1} = tanh(P0 + h0_{i-2}@Whh0)
//         G2: P1_{i-2} = h0_{i-2}@Wih1+b1 ; G3: h1_{i-3} = tanh(P1 + h1_{i-4}@Whh1)
// h/P: atomic-store -> IF; A-reads: 16B sc1 loads from IF.

__global__ __launch_bounds__(512, 2) void rnn4(
    const float* __restrict__ emb,      // [V][1024] f32 (read-only: plain loads)
    const int* __restrict__ tokens,     // [B][T] int32 or int64 (sniffed)
    const unsigned short* __restrict__ Wih0T,  // [2048][1024] fp16
    const unsigned short* __restrict__ Whh0T,  // [2048][2048]
    const unsigned short* __restrict__ Wih1T,  // [2048][2048]
    const unsigned short* __restrict__ Whh1T,  // [2048][2048]
    const float* __restrict__ b0,
    const float* __restrict__ b1,
    unsigned short* __restrict__ h0,    // [2][BH] zeroed
    unsigned short* __restrict__ h1,    // [2][BH] zeroed
    unsigned short* __restrict__ P0,    // [2][BH]
    unsigned short* __restrict__ P1a,   // [2][BH]
    unsigned short* __restrict__ P1b,   // [2][BH]
    const int* __restrict__ lengths,
    unsigned* __restrict__ zp)          // zeroed control page
{
  extern __shared__ char lds[];
  char* Wl = lds;
  char* zone = lds + 131072;

  const int bid = blockIdx.x;
  const int grp = bid >> 5, sub = bid & 31;
  const int tid = threadIdx.x, l = tid & 63, w = tid >> 6;
  const int mw = w & 1, kw = w >> 1;          // 2 M-halves x 4 K-slices
  const int fr = l & 15, q = l >> 4;

  unsigned* gc  = zp;
  unsigned* arr = zp + 64 + grp * 64;

  int role = -1, tile = 0;
  if (grp == 0){ role = 0; tile = sub; }
  else if (grp <= 2){ role = 1; tile = (grp - 1) * 32 + sub; }
  else if (grp <= 4){ role = 2; tile = (grp - 3) * 32 + sub; }
  else if (grp <= 6){ role = 3; tile = (grp - 5) * 32 + sub; }

  const int kh = (role == 2) ? (tile & 1) : 0;
  const int c0 = (role == 0) ? tile * 64 : (role == 2) ? (tile >> 1) * 64 : tile * 32;

  // ---- fill W slice into swizzled LDS (once; read-only inputs, plain loads) ----
  if (role >= 0){
    const unsigned short* src; int NC, KC, srcK, kofs;
    if (role == 0){ src = Wih0T; NC = 64; KC = 1024; srcK = 1024; kofs = 0; }
    else if (role == 2){ src = Wih1T; NC = 64; KC = 1024; srcK = 2048; kofs = kh * 1024; }
    else { src = (role == 1) ? Whh0T : Whh1T; NC = 32; KC = 2048; srcK = 2048; kofs = 0; }
    int nch = NC * (KC / 8);
    for (int i2 = tid; i2 < nch; i2 += 512){
      int c = i2 / (KC / 8), kg = i2 % (KC / 8);
      uint4 v = *(const uint4*)(src + (size_t)(c0 + c) * srcK + kofs + kg * 8);
      int byte = (c * KC + kg * 8) * 2 ^ ((c & 31) << 4);
      *(uint4*)(Wl + byte) = v;
    }
  }
  __syncthreads();

  bool w64 = false;
  if (grp == 0) w64 = ((tokens[1] | tokens[3] | tokens[5] | tokens[7]) == 0);

  int lenr[4][4];
  if (role == 1 || role == 3){
    #pragma unroll
    for (int mt = 0; mt < 4; ++mt)
      #pragma unroll
      for (int r = 0; r < 4; ++r)
        lenr[mt][r] = lengths[mw * 64 + mt * 16 + q * 4 + r];
  }
  float biasv[4] = {0.f, 0.f, 0.f, 0.f};
  if (role == 0){
    #pragma unroll
    for (int nt = 0; nt < 4; ++nt) biasv[nt] = b0[c0 + nt * 16 + fr];
  } else if (role == 2 && kh == 0){
    #pragma unroll
    for (int nt = 0; nt < 4; ++nt) biasv[nt] = b1[c0 + nt * 16 + fr];
  }
  float hp[4][2][4];                      // register-carried h_prev (hh roles, kw==0)
  #pragma unroll
  for (int a = 0; a < 4; ++a)
    #pragma unroll
    for (int b = 0; b < 2; ++b)
      #pragma unroll
      for (int c = 0; c < 4; ++c) hp[a][b][c] = 0.f;

  for (int it = 0; it < 515; ++it){
    if (role == 0){
      // ======== ih0: A = emb rows (plain f32 + cvt), MT=4 NT=4 KF=8 ========
      const int t = it;
      if (t <= 511){
        const int KC = 1024;
        int bb[4], swz[4];
        #pragma unroll
        for (int nt = 0; nt < 4; ++nt){
          int cl = nt * 16 + fr;
          bb[nt] = (cl * KC + kw * 256 + q * 8) * 2;
          swz[nt] = (cl & 31) << 4;
        }
        const char* ap[4];
        #pragma unroll
        for (int mt = 0; mt < 4; ++mt){
          int row = mw * 64 + mt * 16 + fr;
          long idx = (long)row * Tq + t;
          int tok = w64 ? tokens[2 * idx] : tokens[idx];
          ap[mt] = (const char*)(emb + (size_t)tok * Dq) + kw * 1024 + q * 32;  // f32 bytes
        }
        f4 acc[4][4] = {};
        mmX<4, 4, 8, 2>(acc, ap, Wl, bb, swz);

        unsigned short* dst = P0 + (t & 1) * BH;
        #pragma unroll
        for (int mwr = 0; mwr < 2; ++mwr){
          __syncthreads();
          if (mw == mwr && kw > 0){
            #pragma unroll
            for (int mt = 0; mt < 4; ++mt)
              #pragma unroll
              for (int nt = 0; nt < 4; ++nt){
                ushort4 u = { f2h(acc[mt][nt][0]), f2h(acc[mt][nt][1]),
                              f2h(acc[mt][nt][2]), f2h(acc[mt][nt][3]) };
                *(ushort4*)(zone + (kw - 1) * 8192 + (mt * 4 + nt) * 512 + l * 8) = u;
              }
          }
          __syncthreads();
          if (mw == mwr && kw == 0){
            #pragma unroll
            for (int mt = 0; mt < 4; ++mt)
              #pragma unroll
              for (int nt = 0; nt < 4; ++nt){
                f4 s = acc[mt][nt];
                #pragma unroll
                for (int j = 0; j < 3; ++j){
                  ushort4 u = *(ushort4*)(zone + j * 8192 + (mt * 4 + nt) * 512 + l * 8);
                  s[0] += h2f(u.x); s[1] += h2f(u.y); s[2] += h2f(u.z); s[3] += h2f(u.w);
                }
                int col = c0 + nt * 16 + fr;
                #pragma unroll
                for (int r = 0; r < 4; ++r){
                  int row = mw * 64 + mt * 16 + q * 4 + r;
                  st_h(&dst[(size_t)row * Hq + col], f2h(s[r] + biasv[nt]));
                }
              }
          }
        }
      }
    } else if (role == 2){
      // ======== ih1: A = h0_{it-2} via sc1 16B, MT=4 NT=4 KF=8, K-half kh ========
      const int t = it - 2;
      if (t >= 0 && t <= 511){
        const int KC = 1024;
        int bb[4], swz[4];
        #pragma unroll
        for (int nt = 0; nt < 4; ++nt){
          int cl = nt * 16 + fr;
          bb[nt] = (cl * KC + kw * 256 + q * 8) * 2;
          swz[nt] = (cl & 31) << 4;
        }
        const unsigned short* hsrc = h0 + (it & 1) * BH;   // h0_{it-2}
        const char* ap[4];
        #pragma unroll
        for (int mt = 0; mt < 4; ++mt){
          int row = mw * 64 + mt * 16 + fr;
          ap[mt] = (const char*)(hsrc + (size_t)row * Hq + kh * 1024 + kw * 256 + q * 8);
        }
        f4 acc[4][4] = {};
        mmX<4, 4, 8, 1>(acc, ap, Wl, bb, swz);

        unsigned short* dst = (kh == 0 ? P1a : P1b) + (t & 1) * BH;
        #pragma unroll
        for (int mwr = 0; mwr < 2; ++mwr){
          __syncthreads();
          if (mw == mwr && kw > 0){
            #pragma unroll
            for (int mt = 0; mt < 4; ++mt)
              #pragma unroll
              for (int nt = 0; nt < 4; ++nt){
                ushort4 u = { f2h(acc[mt][nt][0]), f2h(acc[mt][nt][1]),
                              f2h(acc[mt][nt][2]), f2h(acc[mt][nt][3]) };
                *(ushort4*)(zone + (kw - 1) * 8192 + (mt * 4 + nt) * 512 + l * 8) = u;
              }
          }
          __syncthreads();
          if (mw == mwr && kw == 0){
            #pragma unroll
            for (int mt = 0; mt < 4; ++mt)
              #pragma unroll
              for (int nt = 0; nt < 4; ++nt){
                f4 s = acc[mt][nt];
                #pragma unroll
                for (int j = 0; j < 3; ++j){
                  ushort4 u = *(ushort4*)(zone + j * 8192 + (mt * 4 + nt) * 512 + l * 8);
                  s[0] += h2f(u.x); s[1] += h2f(u.y); s[2] += h2f(u.z); s[3] += h2f(u.w);
                }
                int col = c0 + nt * 16 + fr;
                #pragma unroll
                for (int r = 0; r < 4; ++r){
                  int row = mw * 64 + mt * 16 + q * 4 + r;
                  st_h(&dst[(size_t)row * Hq + col], f2h(s[r] + biasv[nt]));
                }
              }
          }
        }
      }
    } else if (role == 1 || role == 3){
      // ======== hh: A = h_{t-1} via sc1 16B, MT=4 NT=2 KF=16 ========
      const int t = (role == 1) ? it - 1 : it - 3;
      if (t >= 0 && t <= 511){
        const int KC = 2048;
        int bb[2], swz[2];
        #pragma unroll
        for (int nt = 0; nt < 2; ++nt){
          int cl = nt * 16 + fr;
          bb[nt] = (cl * KC + kw * 512 + q * 8) * 2;
          swz[nt] = (cl & 31) << 4;
        }
        unsigned short* hbuf = (role == 1) ? h0 : h1;
        const unsigned short* hsrc = hbuf + (it & 1) * BH;   // h_{t-1}
        const char* ap[4];
        #pragma unroll
        for (int mt = 0; mt < 4; ++mt){
          int row = mw * 64 + mt * 16 + fr;
          ap[mt] = (const char*)(hsrc + (size_t)row * Hq + kw * 512 + q * 8);
        }
        f4 acc[4][2] = {};
        mmX<4, 2, 16, 1>(acc, ap, Wl, bb, swz);

        const unsigned short* Pa = ((role == 1) ? P0 : P1a) + (t & 1) * BH;
        const unsigned short* Pb = (role == 3) ? (P1b + (t & 1) * BH) : nullptr;
        unsigned short* hdst = hbuf + (t & 1) * BH;
        #pragma unroll
        for (int mwr = 0; mwr < 2; ++mwr){
          __syncthreads();
          if (mw == mwr && kw > 0){
            #pragma unroll
            for (int mt = 0; mt < 4; ++mt)
              #pragma unroll
              for (int nt = 0; nt < 2; ++nt){
                ushort4 u = { f2h(acc[mt][nt][0]), f2h(acc[mt][nt][1]),
                              f2h(acc[mt][nt][2]), f2h(acc[mt][nt][3]) };
                *(ushort4*)(zone + (kw - 1) * 8192 + (mt * 2 + nt) * 512 + l * 8) = u;
              }
          }
          __syncthreads();
          if (mw == mwr && kw == 0){
            #pragma unroll
            for (int mt = 0; mt < 4; ++mt)
              #pragma unroll
              for (int nt = 0; nt < 2; ++nt){
                f4 s = acc[mt][nt];
                #pragma unroll
                for (int j = 0; j < 3; ++j){
                  ushort4 u = *(ushort4*)(zone + j * 8192 + (mt * 2 + nt) * 512 + l * 8);
                  s[0] += h2f(u.x); s[1] += h2f(u.y); s[2] += h2f(u.z); s[3] += h2f(u.w);
                }
                int col = c0 + nt * 16 + fr;
                #pragma unroll
                for (int r = 0; r < 4; ++r){
                  int row = mw * 64 + mt * 16 + q * 4 + r;
                  size_t o = (size_t)row * Hq + col;
                  float v = s[r] + h2f(ld_h(&Pa[o]));
                  if (role == 3) v += h2f(ld_h(&Pb[o]));
                  float hn = fast_tanh(v);
                  float ho = (t < lenr[mt][r]) ? hn : hp[mt][nt][r];
                  hp[mt][nt][r] = ho;
                  st_h(&hdst[o], f2h(ho));
                }
              }
          }
        }
      }
    }
    if (it < 514) gbar(arr, gc, sub, it);
  }
}

// ---------------- launch ----------------

extern "C" void kernel_launch(void* const* d_in, const int* in_sizes, int n_in,
                              void* d_out, int out_size, void* d_ws, size_t ws_size,
                              hipStream_t stream)
{
  (void)in_sizes; (void)n_in; (void)out_size; (void)ws_size;
  const int*   tokens  = (const int*)d_in[0];
  const int*   lengths = (const int*)d_in[1];
  const float* emb     = (const float*)d_in[2];
  const float* Wih0    = (const float*)d_in[3];
  const float* Whh0    = (const float*)d_in[4];
  const float* b0      = (const float*)d_in[5];
  const float* Wih1    = (const float*)d_in[6];
  const float* Whh1    = (const float*)d_in[7];
  const float* b1      = (const float*)d_in[8];

  char* ws = (char*)d_ws;
  size_t off = 0;
  auto alloc = [&](size_t bytes)->char*{
    char* p = ws + off; off += (bytes + 255) & ~(size_t)255; return p;
  };
  unsigned short* WTih0 = (unsigned short*)alloc((size_t)Hq * Dq * 2);   //  4 MB
  unsigned short* WThh0 = (unsigned short*)alloc((size_t)Hq * Hq * 2);   //  8 MB
  unsigned short* WTih1 = (unsigned short*)alloc((size_t)Hq * Hq * 2);   //  8 MB
  unsigned short* WThh1 = (unsigned short*)alloc((size_t)Hq * Hq * 2);   //  8 MB
  unsigned short* h0b   = (unsigned short*)alloc((size_t)2 * BH * 2);    //  1 MB
  unsigned short* h1b   = (unsigned short*)alloc((size_t)2 * BH * 2);
  unsigned short* P0b   = (unsigned short*)alloc((size_t)2 * BH * 2);
  unsigned short* P1ab  = (unsigned short*)alloc((size_t)2 * BH * 2);
  unsigned short* P1bb  = (unsigned short*)alloc((size_t)2 * BH * 2);
  unsigned*       zp    = (unsigned*)alloc(4096);
  // total ~34 MB

  transpose_cast<<<dim3(Hq / 32, Dq / 32), dim3(32, 8), 0, stream>>>(Wih0, WTih0, Dq, Hq);
  transpose_cast<<<dim3(Hq / 32, Hq / 32), dim3(32, 8), 0, stream>>>(Whh0, WThh0, Hq, Hq);
  transpose_cast<<<dim3(Hq / 32, Hq / 32), dim3(32, 8), 0, stream>>>(Wih1, WTih1, Hq, Hq);
  transpose_cast<<<dim3(Hq / 32, Hq / 32), dim3(32, 8), 0, stream>>>(Whh1, WThh1, Hq, Hq);

  hipMemsetAsync(h0b, 0, (size_t)2 * BH * 2, stream);
  hipMemsetAsync(h1b, 0, (size_t)2 * BH * 2, stream);
  hipMemsetAsync(zp, 0, 4096, stream);

  hipFuncSetAttribute((const void*)rnn4, hipFuncAttributeMaxDynamicSharedMemorySize, 155648);
  rnn4<<<256, 512, 155648, stream>>>(emb, tokens, WTih0, WThh0, WTih1, WThh1,
                                     b0, b1, h0b, h1b, P0b, P1ab, P1bb,
                                     lengths, zp);

  h2f_out<<<(BH + 255) / 256, 256, 0, stream>>>(h1b + BH, (float*)d_out, BH);
}

// Round 10
// 34494.870 us; speedup vs baseline: 1.2126x; 1.0402x over previous
//
#include <hip/hip_runtime.h>
#include <stdint.h>
#include <stddef.h>

#define Bq 128
#define Tq 512
#define Vq 32000
#define Dq 1024
#define Hq 2048
#define BH (Bq * Hq)

typedef __attribute__((ext_vector_type(8))) _Float16 h8;   // 8 x fp16
typedef __attribute__((ext_vector_type(4))) float f4;
typedef unsigned long long ull;

__device__ __forceinline__ float h2f(unsigned short u){
  _Float16 h; __builtin_memcpy(&h, &u, 2); return (float)h;
}
__device__ __forceinline__ unsigned short f2h(float f){
  _Float16 h = (_Float16)f; unsigned short u; __builtin_memcpy(&u, &h, 2); return u;
}
__device__ __forceinline__ float fast_tanh(float x){
  float e = __expf(2.0f * x);
  return 1.0f - 2.0f / (e + 1.0f);
}

// ---- cross-block primitives: agent-scope atomics (proven r7/r9) ----
// st_h: atomic store agent-scope -> sc1 write-through; completed at IF when
// vmcnt-acked, so a later relaxed flag bump cannot pass it (r10 relies on this).
__device__ __forceinline__ void st_h(unsigned short* p, unsigned short v){
  __hip_atomic_store(p, v, __ATOMIC_RELAXED, __HIP_MEMORY_SCOPE_AGENT);
}
__device__ __forceinline__ unsigned short ld_h(const unsigned short* p){
  return __hip_atomic_load(p, __ATOMIC_RELAXED, __HIP_MEMORY_SCOPE_AGENT);
}
__device__ __forceinline__ unsigned ld_u(const unsigned* p){
  return __hip_atomic_load(p, __ATOMIC_RELAXED, __HIP_MEMORY_SCOPE_AGENT);
}
__device__ __forceinline__ unsigned add_u(unsigned* p, unsigned v){
  return __hip_atomic_fetch_add(p, v, __ATOMIC_RELAXED, __HIP_MEMORY_SCOPE_AGENT);
}

// 16B load, L2-bypass (sc1) -> reads IF; coherent with agent-atomic stores.
__device__ __forceinline__ h8 ald16(const void* p){
  h8 d;
  asm volatile("global_load_dwordx4 %0, %1, off sc1" : "=v"(d) : "v"(p));
  return d;
}
template<int N>
__device__ __forceinline__ void vwait(){
  asm volatile("s_waitcnt vmcnt(%0)" :: "i"(N) : "memory");
  __builtin_amdgcn_sched_barrier(0);   // rule #18: pin consumers below the wait
}

// ---------------- preprocessing ----------------

// in[K][N] f32 -> out[N][K] fp16
__global__ void transpose_cast(const float* __restrict__ in, unsigned short* __restrict__ out, int K, int N){
  __shared__ float tile[32][33];
  int n0 = blockIdx.x * 32, k0 = blockIdx.y * 32;
  int tx = threadIdx.x, ty = threadIdx.y;
  #pragma unroll
  for (int i = 0; i < 32; i += 8)
    tile[ty + i][tx] = in[(size_t)(k0 + ty + i) * N + n0 + tx];
  __syncthreads();
  #pragma unroll
  for (int i = 0; i < 32; i += 8)
    out[(size_t)(n0 + ty + i) * K + k0 + tx] = f2h(tile[tx][ty + i]);
}

__global__ void h2f_out(const unsigned short* __restrict__ in, float* __restrict__ out, int n){
  int i = blockIdx.x * blockDim.x + threadIdx.x;
  if (i < n) out[i] = h2f(in[i]);
}

// ---------------- inner GEMM: acc[MT][NT] += A x B(LDS swizzled) ----------------
// MODE 1: A via 16B sc1 asm loads; vmcnt(3MT/2MT/MT/0) ladder; batch kf+4
//   issued into slot kf&3 AFTER the kf MFMAs consume it (r9-verified order).
// MODE 2: A via plain f32 loads + in-register fp16 convert (read-only emb).

template<int MT, int NT, int KF, int MODE>
__device__ __forceinline__ void mmX(f4 (&acc)[MT][NT],
    const char* const (&ap)[MT], const char* Wl,
    const int (&bb)[NT], const int (&swz)[NT])
{
  h8 ab[4][MT];
  auto lda2 = [&](int kf, int mt) -> h8 {   // MODE 2 only
    const float4* p = (const float4*)(ap[mt] + kf * 128);
    float4 x = p[0], y = p[1];
    h8 h;
    h[0] = (_Float16)x.x; h[1] = (_Float16)x.y; h[2] = (_Float16)x.z; h[3] = (_Float16)x.w;
    h[4] = (_Float16)y.x; h[5] = (_Float16)y.y; h[6] = (_Float16)y.z; h[7] = (_Float16)y.w;
    return h;
  };

  #pragma unroll
  for (int kf = 0; kf < 4 && kf < KF; ++kf)
    #pragma unroll
    for (int mt = 0; mt < MT; ++mt){
      if constexpr (MODE == 1) ab[kf][mt] = ald16(ap[mt] + kf * 64);
      else                     ab[kf][mt] = lda2(kf, mt);
    }

  #pragma unroll
  for (int kf = 0; kf < KF; ++kf){
    if constexpr (MODE == 1){
      const int rem = KF - 1 - kf;
      if (rem >= 3) vwait<3*MT>();
      else if (rem == 2) vwait<2*MT>();
      else if (rem == 1) vwait<MT>();
      else vwait<0>();
    }
    h8 b[NT];
    #pragma unroll
    for (int nt = 0; nt < NT; ++nt)
      b[nt] = *(const h8*)(Wl + ((bb[nt] + kf * 64) ^ swz[nt]));
    #pragma unroll
    for (int mt = 0; mt < MT; ++mt)
      #pragma unroll
      for (int nt = 0; nt < NT; ++nt)
        acc[mt][nt] = __builtin_amdgcn_mfma_f32_16x16x32_f16(ab[kf & 3][mt], b[nt], acc[mt][nt], 0, 0, 0);
    if (kf + 4 < KF){                       // issue AFTER consumption
      #pragma unroll
      for (int mt = 0; mt < MT; ++mt){
        if constexpr (MODE == 1) ab[kf & 3][mt] = ald16(ap[mt] + (kf + 4) * 64);
        else                     ab[kf & 3][mt] = lda2(kf + 4, mt);
      }
    }
  }
}

// ---------------- grid barrier: ALL-RELAXED (r10 change) ----------------
// Data stores are sc1 write-through atomics, already at IF when the
// __syncthreads vmcnt(0) drain completes -> no release/wbl2 needed.

__device__ __forceinline__ void gbar(unsigned* arr, unsigned* gc, int sub, int it){
  __syncthreads();                               // drains vmcnt: sc1 stores at IF
  if (threadIdx.x == 0){
    add_u(arr, 1u);
    if (sub == 0){
      while (ld_u(arr) < 32u * (unsigned)(it + 1)) __builtin_amdgcn_s_sleep(1);
      add_u(gc, 1u);
    }
    while (ld_u(gc) < 8u * (unsigned)(it + 1)) __builtin_amdgcn_s_sleep(1);
    asm volatile("" ::: "memory");
  }
  __syncthreads();
}

// ---------------- 4-role persistent pipeline (placement-independent) ----------------
// grp = bid>>5: g0=ih0(32) g1,2=hh0(64) g3,4=ih1(64) g5,6=hh1(64) g7=idle(32)
// iter i: G0: P0_i = emb[tok_i]@Wih0+b0 ; G1: h0_{i-1} = tanh(P0 + h0_{i-2}@Whh0)
//         G2: P1_{i-2} = h0_{i-2}@Wih1+b1 ; G3: h1_{i-3} = tanh(P1 + h1_{i-4}@Whh1)
// h/P: sc1 atomic-store -> IF; A-reads: 16B sc1 loads from IF.

__global__ __launch_bounds__(512, 2) void rnn4(
    const float* __restrict__ emb,      // [V][1024] f32 (read-only: plain loads)
    const int* __restrict__ tokens,     // [B][T] int32 or int64 (sniffed)
    const unsigned short* __restrict__ Wih0T,  // [2048][1024] fp16
    const unsigned short* __restrict__ Whh0T,  // [2048][2048]
    const unsigned short* __restrict__ Wih1T,  // [2048][2048]
    const unsigned short* __restrict__ Whh1T,  // [2048][2048]
    const float* __restrict__ b0,
    const float* __restrict__ b1,
    unsigned short* __restrict__ h0,    // [2][BH] zeroed
    unsigned short* __restrict__ h1,    // [2][BH] zeroed
    unsigned short* __restrict__ P0,    // [2][BH]
    unsigned short* __restrict__ P1a,   // [2][BH]
    unsigned short* __restrict__ P1b,   // [2][BH]
    const int* __restrict__ lengths,
    unsigned* __restrict__ zp)          // zeroed control page
{
  extern __shared__ char lds[];
  char* Wl = lds;
  char* zone = lds + 131072;

  const int bid = blockIdx.x;
  const int grp = bid >> 5, sub = bid & 31;
  const int tid = threadIdx.x, l = tid & 63, w = tid >> 6;
  const int mw = w & 1, kw = w >> 1;          // 2 M-halves x 4 K-slices
  const int fr = l & 15, q = l >> 4;

  unsigned* gc  = zp;
  unsigned* arr = zp + 64 + grp * 64;

  int role = -1, tile = 0;
  if (grp == 0){ role = 0; tile = sub; }
  else if (grp <= 2){ role = 1; tile = (grp - 1) * 32 + sub; }
  else if (grp <= 4){ role = 2; tile = (grp - 3) * 32 + sub; }
  else if (grp <= 6){ role = 3; tile = (grp - 5) * 32 + sub; }

  const int kh = (role == 2) ? (tile & 1) : 0;
  const int c0 = (role == 0) ? tile * 64 : (role == 2) ? (tile >> 1) * 64 : tile * 32;

  // ---- fill W slice into swizzled LDS (once; read-only inputs, plain loads) ----
  if (role >= 0){
    const unsigned short* src; int NC, KC, srcK, kofs;
    if (role == 0){ src = Wih0T; NC = 64; KC = 1024; srcK = 1024; kofs = 0; }
    else if (role == 2){ src = Wih1T; NC = 64; KC = 1024; srcK = 2048; kofs = kh * 1024; }
    else { src = (role == 1) ? Whh0T : Whh1T; NC = 32; KC = 2048; srcK = 2048; kofs = 0; }
    int nch = NC * (KC / 8);
    for (int i2 = tid; i2 < nch; i2 += 512){
      int c = i2 / (KC / 8), kg = i2 % (KC / 8);
      uint4 v = *(const uint4*)(src + (size_t)(c0 + c) * srcK + kofs + kg * 8);
      int byte = (c * KC + kg * 8) * 2 ^ ((c & 31) << 4);
      *(uint4*)(Wl + byte) = v;
    }
  }
  __syncthreads();

  bool w64 = false;
  if (grp == 0) w64 = ((tokens[1] | tokens[3] | tokens[5] | tokens[7]) == 0);

  int lenr[4][4];
  if (role == 1 || role == 3){
    #pragma unroll
    for (int mt = 0; mt < 4; ++mt)
      #pragma unroll
      for (int r = 0; r < 4; ++r)
        lenr[mt][r] = lengths[mw * 64 + mt * 16 + q * 4 + r];
  }
  float biasv[4] = {0.f, 0.f, 0.f, 0.f};
  if (role == 0){
    #pragma unroll
    for (int nt = 0; nt < 4; ++nt) biasv[nt] = b0[c0 + nt * 16 + fr];
  } else if (role == 2 && kh == 0){
    #pragma unroll
    for (int nt = 0; nt < 4; ++nt) biasv[nt] = b1[c0 + nt * 16 + fr];
  }
  float hp[4][2][4];                      // register-carried h_prev (hh roles, kw==0)
  #pragma unroll
  for (int a = 0; a < 4; ++a)
    #pragma unroll
    for (int b = 0; b < 2; ++b)
      #pragma unroll
      for (int c = 0; c < 4; ++c) hp[a][b][c] = 0.f;

  for (int it = 0; it < 515; ++it){
    if (role == 0){
      // ======== ih0: A = emb rows (plain f32 + cvt), MT=4 NT=4 KF=8 ========
      const int t = it;
      if (t <= 511){
        const int KC = 1024;
        int bb[4], swz[4];
        #pragma unroll
        for (int nt = 0; nt < 4; ++nt){
          int cl = nt * 16 + fr;
          bb[nt] = (cl * KC + kw * 256 + q * 8) * 2;
          swz[nt] = (cl & 31) << 4;
        }
        const char* ap[4];
        #pragma unroll
        for (int mt = 0; mt < 4; ++mt){
          int row = mw * 64 + mt * 16 + fr;
          long idx = (long)row * Tq + t;
          int tok = w64 ? tokens[2 * idx] : tokens[idx];
          ap[mt] = (const char*)(emb + (size_t)tok * Dq) + kw * 1024 + q * 32;  // f32 bytes
        }
        f4 acc[4][4] = {};
        mmX<4, 4, 8, 2>(acc, ap, Wl, bb, swz);

        unsigned short* dst = P0 + (t & 1) * BH;
        #pragma unroll
        for (int mwr = 0; mwr < 2; ++mwr){
          __syncthreads();
          if (mw == mwr && kw > 0){
            #pragma unroll
            for (int mt = 0; mt < 4; ++mt)
              #pragma unroll
              for (int nt = 0; nt < 4; ++nt){
                ushort4 u = { f2h(acc[mt][nt][0]), f2h(acc[mt][nt][1]),
                              f2h(acc[mt][nt][2]), f2h(acc[mt][nt][3]) };
                *(ushort4*)(zone + (kw - 1) * 8192 + (mt * 4 + nt) * 512 + l * 8) = u;
              }
          }
          __syncthreads();
          if (mw == mwr && kw == 0){
            #pragma unroll
            for (int mt = 0; mt < 4; ++mt)
              #pragma unroll
              for (int nt = 0; nt < 4; ++nt){
                f4 s = acc[mt][nt];
                #pragma unroll
                for (int j = 0; j < 3; ++j){
                  ushort4 u = *(ushort4*)(zone + j * 8192 + (mt * 4 + nt) * 512 + l * 8);
                  s[0] += h2f(u.x); s[1] += h2f(u.y); s[2] += h2f(u.z); s[3] += h2f(u.w);
                }
                int col = c0 + nt * 16 + fr;
                #pragma unroll
                for (int r = 0; r < 4; ++r){
                  int row = mw * 64 + mt * 16 + q * 4 + r;
                  st_h(&dst[(size_t)row * Hq + col], f2h(s[r] + biasv[nt]));
                }
              }
          }
        }
      }
    } else if (role == 2){
      // ======== ih1: A = h0_{it-2} via sc1 16B, MT=4 NT=4 KF=8, K-half kh ========
      const int t = it - 2;
      if (t >= 0 && t <= 511){
        const int KC = 1024;
        int bb[4], swz[4];
        #pragma unroll
        for (int nt = 0; nt < 4; ++nt){
          int cl = nt * 16 + fr;
          bb[nt] = (cl * KC + kw * 256 + q * 8) * 2;
          swz[nt] = (cl & 31) << 4;
        }
        const unsigned short* hsrc = h0 + (it & 1) * BH;   // h0_{it-2}
        const char* ap[4];
        #pragma unroll
        for (int mt = 0; mt < 4; ++mt){
          int row = mw * 64 + mt * 16 + fr;
          ap[mt] = (const char*)(hsrc + (size_t)row * Hq + kh * 1024 + kw * 256 + q * 8);
        }
        f4 acc[4][4] = {};
        mmX<4, 4, 8, 1>(acc, ap, Wl, bb, swz);

        unsigned short* dst = (kh == 0 ? P1a : P1b) + (t & 1) * BH;
        #pragma unroll
        for (int mwr = 0; mwr < 2; ++mwr){
          __syncthreads();
          if (mw == mwr && kw > 0){
            #pragma unroll
            for (int mt = 0; mt < 4; ++mt)
              #pragma unroll
              for (int nt = 0; nt < 4; ++nt){
                ushort4 u = { f2h(acc[mt][nt][0]), f2h(acc[mt][nt][1]),
                              f2h(acc[mt][nt][2]), f2h(acc[mt][nt][3]) };
                *(ushort4*)(zone + (kw - 1) * 8192 + (mt * 4 + nt) * 512 + l * 8) = u;
              }
          }
          __syncthreads();
          if (mw == mwr && kw == 0){
            #pragma unroll
            for (int mt = 0; mt < 4; ++mt)
              #pragma unroll
              for (int nt = 0; nt < 4; ++nt){
                f4 s = acc[mt][nt];
                #pragma unroll
                for (int j = 0; j < 3; ++j){
                  ushort4 u = *(ushort4*)(zone + j * 8192 + (mt * 4 + nt) * 512 + l * 8);
                  s[0] += h2f(u.x); s[1] += h2f(u.y); s[2] += h2f(u.z); s[3] += h2f(u.w);
                }
                int col = c0 + nt * 16 + fr;
                #pragma unroll
                for (int r = 0; r < 4; ++r){
                  int row = mw * 64 + mt * 16 + q * 4 + r;
                  st_h(&dst[(size_t)row * Hq + col], f2h(s[r] + biasv[nt]));
                }
              }
          }
        }
      }
    } else if (role == 1 || role == 3){
      // ======== hh: A = h_{t-1} via sc1 16B, MT=4 NT=2 KF=16 ========
      const int t = (role == 1) ? it - 1 : it - 3;
      if (t >= 0 && t <= 511){
        const int KC = 2048;
        int bb[2], swz[2];
        #pragma unroll
        for (int nt = 0; nt < 2; ++nt){
          int cl = nt * 16 + fr;
          bb[nt] = (cl * KC + kw * 512 + q * 8) * 2;
          swz[nt] = (cl & 31) << 4;
        }
        unsigned short* hbuf = (role == 1) ? h0 : h1;
        const unsigned short* hsrc = hbuf + (it & 1) * BH;   // h_{t-1}
        const char* ap[4];
        #pragma unroll
        for (int mt = 0; mt < 4; ++mt){
          int row = mw * 64 + mt * 16 + fr;
          ap[mt] = (const char*)(hsrc + (size_t)row * Hq + kw * 512 + q * 8);
        }
        f4 acc[4][2] = {};
        mmX<4, 2, 16, 1>(acc, ap, Wl, bb, swz);

        const unsigned short* Pa = ((role == 1) ? P0 : P1a) + (t & 1) * BH;
        const unsigned short* Pb = (role == 3) ? (P1b + (t & 1) * BH) : nullptr;
        unsigned short* hdst = hbuf + (t & 1) * BH;
        #pragma unroll
        for (int mwr = 0; mwr < 2; ++mwr){
          __syncthreads();
          if (mw == mwr && kw > 0){
            #pragma unroll
            for (int mt = 0; mt < 4; ++mt)
              #pragma unroll
              for (int nt = 0; nt < 2; ++nt){
                ushort4 u = { f2h(acc[mt][nt][0]), f2h(acc[mt][nt][1]),
                              f2h(acc[mt][nt][2]), f2h(acc[mt][nt][3]) };
                *(ushort4*)(zone + (kw - 1) * 8192 + (mt * 2 + nt) * 512 + l * 8) = u;
              }
          }
          __syncthreads();
          if (mw == mwr && kw == 0){
            #pragma unroll
            for (int mt = 0; mt < 4; ++mt)
              #pragma unroll
              for (int nt = 0; nt < 2; ++nt){
                f4 s = acc[mt][nt];
                #pragma unroll
                for (int j = 0; j < 3; ++j){
                  ushort4 u = *(ushort4*)(zone + j * 8192 + (mt * 2 + nt) * 512 + l * 8);
                  s[0] += h2f(u.x); s[1] += h2f(u.y); s[2] += h2f(u.z); s[3] += h2f(u.w);
                }
                int col = c0 + nt * 16 + fr;
                #pragma unroll
                for (int r = 0; r < 4; ++r){
                  int row = mw * 64 + mt * 16 + q * 4 + r;
                  size_t o = (size_t)row * Hq + col;
                  float v = s[r] + h2f(ld_h(&Pa[o]));
                  if (role == 3) v += h2f(ld_h(&Pb[o]));
                  float hn = fast_tanh(v);
                  float ho = (t < lenr[mt][r]) ? hn : hp[mt][nt][r];
                  hp[mt][nt][r] = ho;
                  st_h(&hdst[o], f2h(ho));
                }
              }
          }
        }
      }
    }
    if (it < 514) gbar(arr, gc, sub, it);
  }
}

// ---------------- launch ----------------

extern "C" void kernel_launch(void* const* d_in, const int* in_sizes, int n_in,
                              void* d_out, int out_size, void* d_ws, size_t ws_size,
                              hipStream_t stream)
{
  (void)in_sizes; (void)n_in; (void)out_size; (void)ws_size;
  const int*   tokens  = (const int*)d_in[0];
  const int*   lengths = (const int*)d_in[1];
  const float* emb     = (const float*)d_in[2];
  const float* Wih0    = (const float*)d_in[3];
  const float* Whh0    = (const float*)d_in[4];
  const float* b0      = (const float*)d_in[5];
  const float* Wih1    = (const float*)d_in[6];
  const float* Whh1    = (const float*)d_in[7];
  const float* b1      = (const float*)d_in[8];

  char* ws = (char*)d_ws;
  size_t off = 0;
  auto alloc = [&](size_t bytes)->char*{
    char* p = ws + off; off += (bytes + 255) & ~(size_t)255; return p;
  };
  unsigned short* WTih0 = (unsigned short*)alloc((size_t)Hq * Dq * 2);   //  4 MB
  unsigned short* WThh0 = (unsigned short*)alloc((size_t)Hq * Hq * 2);   //  8 MB
  unsigned short* WTih1 = (unsigned short*)alloc((size_t)Hq * Hq * 2);   //  8 MB
  unsigned short* WThh1 = (unsigned short*)alloc((size_t)Hq * Hq * 2);   //  8 MB
  unsigned short* h0b   = (unsigned short*)alloc((size_t)2 * BH * 2);    //  1 MB
  unsigned short* h1b   = (unsigned short*)alloc((size_t)2 * BH * 2);
  unsigned short* P0b   = (unsigned short*)alloc((size_t)2 * BH * 2);
  unsigned short* P1ab  = (unsigned short*)alloc((size_t)2 * BH * 2);
  unsigned short* P1bb  = (unsigned short*)alloc((size_t)2 * BH * 2);
  unsigned*       zp    = (unsigned*)alloc(4096);
  // total ~34 MB

  transpose_cast<<<dim3(Hq / 32, Dq / 32), dim3(32, 8), 0, stream>>>(Wih0, WTih0, Dq, Hq);
  transpose_cast<<<dim3(Hq / 32, Hq / 32), dim3(32, 8), 0, stream>>>(Whh0, WThh0, Hq, Hq);
  transpose_cast<<<dim3(Hq / 32, Hq / 32), dim3(32, 8), 0, stream>>>(Wih1, WTih1, Hq, Hq);
  transpose_cast<<<dim3(Hq / 32, Hq / 32), dim3(32, 8), 0, stream>>>(Whh1, WThh1, Hq, Hq);

  hipMemsetAsync(h0b, 0, (size_t)2 * BH * 2, stream);
  hipMemsetAsync(h1b, 0, (size_t)2 * BH * 2, stream);
  hipMemsetAsync(zp, 0, 4096, stream);

  hipFuncSetAttribute((const void*)rnn4, hipFuncAttributeMaxDynamicSharedMemorySize, 155648);
  rnn4<<<256, 512, 155648, stream>>>(emb, tokens, WTih0, WThh0, WTih1, WThh1,
                                     b0, b1, h0b, h1b, P0b, P1ab, P1bb,
                                     lengths, zp);

  h2f_out<<<(BH + 255) / 256, 256, 0, stream>>>(h1b + BH, (float*)d_out, BH);
}

// Round 11
// 14580.347 us; speedup vs baseline: 2.8687x; 2.3658x over previous
//
#include <hip/hip_runtime.h>
#include <stdint.h>
#include <stddef.h>

#define Bq 128
#define Tq 512
#define Vq 32000
#define Dq 1024
#define Hq 2048
#define BH (Bq * Hq)

typedef __attribute__((ext_vector_type(8))) _Float16 h8;   // 8 x fp16
typedef __attribute__((ext_vector_type(4))) float f4;
typedef unsigned long long ull;

__device__ __forceinline__ float h2f(unsigned short u){
  _Float16 h; __builtin_memcpy(&h, &u, 2); return (float)h;
}
__device__ __forceinline__ unsigned short f2h(float f){
  _Float16 h = (_Float16)f; unsigned short u; __builtin_memcpy(&u, &h, 2); return u;
}
__device__ __forceinline__ float fast_tanh(float x){
  float e = __expf(2.0f * x);
  return 1.0f - 2.0f / (e + 1.0f);
}
__device__ __forceinline__ ull pack4h(float a, float b, float c, float d){
  return (ull)f2h(a) | ((ull)f2h(b) << 16) | ((ull)f2h(c) << 32) | ((ull)f2h(d) << 48);
}

// ---- cross-XCD primitives: agent-scope atomics (proven r7/r9/r10) ----
__device__ __forceinline__ ull ld_q(const ull* p){
  return __hip_atomic_load(p, __ATOMIC_RELAXED, __HIP_MEMORY_SCOPE_AGENT);
}
__device__ __forceinline__ void st_q(ull* p, ull v){
  __hip_atomic_store(p, v, __ATOMIC_RELAXED, __HIP_MEMORY_SCOPE_AGENT);
}
__device__ __forceinline__ unsigned ld_u(const unsigned* p){
  return __hip_atomic_load(p, __ATOMIC_RELAXED, __HIP_MEMORY_SCOPE_AGENT);
}
__device__ __forceinline__ unsigned add_u(unsigned* p, unsigned v){
  return __hip_atomic_fetch_add(p, v, __ATOMIC_RELAXED, __HIP_MEMORY_SCOPE_AGENT);
}

// 16B asm loads: SC=1 -> sc0 (L1 bypass, local-L2 hit); SC=2 -> sc1 (IF)
template<int SC>
__device__ __forceinline__ h8 ald16(const void* p){
  h8 d;
  if constexpr (SC == 1)
    asm volatile("global_load_dwordx4 %0, %1, off sc0" : "=v"(d) : "v"(p));
  else
    asm volatile("global_load_dwordx4 %0, %1, off sc1" : "=v"(d) : "v"(p));
  return d;
}
template<int N>
__device__ __forceinline__ void vwait(){
  asm volatile("s_waitcnt vmcnt(%0)" :: "i"(N) : "memory");
  __builtin_amdgcn_sched_barrier(0);
}

// ---------------- preprocessing ----------------

__global__ void transpose_cast(const float* __restrict__ in, unsigned short* __restrict__ out, int K, int N){
  __shared__ float tile[32][33];
  int n0 = blockIdx.x * 32, k0 = blockIdx.y * 32;
  int tx = threadIdx.x, ty = threadIdx.y;
  #pragma unroll
  for (int i = 0; i < 32; i += 8)
    tile[ty + i][tx] = in[(size_t)(k0 + ty + i) * N + n0 + tx];
  __syncthreads();
  #pragma unroll
  for (int i = 0; i < 32; i += 8)
    out[(size_t)(n0 + ty + i) * K + k0 + tx] = f2h(tile[tx][ty + i]);
}

__global__ void h2f_out(const unsigned short* __restrict__ in, float* __restrict__ out, int n){
  int i = blockIdx.x * blockDim.x + threadIdx.x;
  if (i < n) out[i] = h2f(in[i]);
}

// ---------------- inner GEMM: acc[MT][NT] += A x B(LDS swizzled) ----------------
// MODE 1: A via sc1 16B asm loads (IF)        — manual vmcnt ladder
// MODE 3: A via sc0 16B asm loads (local L2)  — manual vmcnt ladder
// MODE 2: A via plain f32 loads + cvt (emb fallback) — compiler waitcnts
// Pipeline: 4 batches of MT in flight; slot kf&3 reloaded AFTER its MFMAs (r9 order).

template<int MT, int NT, int KF, int MODE>
__device__ __forceinline__ void mmX(f4 (&acc)[MT][NT],
    const char* const (&ap)[MT], const char* Wl,
    const int (&bb)[NT], const int (&swz)[NT])
{
  h8 ab[4][MT];
  auto lda2 = [&](int kf, int mt) -> h8 {
    const float4* p = (const float4*)(ap[mt] + kf * 128);
    float4 x = p[0], y = p[1];
    h8 h;
    h[0] = (_Float16)x.x; h[1] = (_Float16)x.y; h[2] = (_Float16)x.z; h[3] = (_Float16)x.w;
    h[4] = (_Float16)y.x; h[5] = (_Float16)y.y; h[6] = (_Float16)y.z; h[7] = (_Float16)y.w;
    return h;
  };
  #pragma unroll
  for (int kf = 0; kf < 4 && kf < KF; ++kf)
    #pragma unroll
    for (int mt = 0; mt < MT; ++mt){
      if constexpr (MODE == 1) ab[kf][mt] = ald16<2>(ap[mt] + kf * 64);
      else if constexpr (MODE == 3) ab[kf][mt] = ald16<1>(ap[mt] + kf * 64);
      else ab[kf][mt] = lda2(kf, mt);
    }
  #pragma unroll
  for (int kf = 0; kf < KF; ++kf){
    if constexpr (MODE != 2){
      const int rem = KF - 1 - kf;
      if (rem >= 3) vwait<3*MT>();
      else if (rem == 2) vwait<2*MT>();
      else if (rem == 1) vwait<MT>();
      else vwait<0>();
    }
    h8 b[NT];
    #pragma unroll
    for (int nt = 0; nt < NT; ++nt)
      b[nt] = *(const h8*)(Wl + ((bb[nt] + kf * 64) ^ swz[nt]));
    #pragma unroll
    for (int mt = 0; mt < MT; ++mt)
      #pragma unroll
      for (int nt = 0; nt < NT; ++nt)
        acc[mt][nt] = __builtin_amdgcn_mfma_f32_16x16x32_f16(ab[kf & 3][mt], b[nt], acc[mt][nt], 0, 0, 0);
    if (kf + 4 < KF){
      #pragma unroll
      for (int mt = 0; mt < MT; ++mt){
        if constexpr (MODE == 1) ab[kf & 3][mt] = ald16<2>(ap[mt] + (kf + 4) * 64);
        else if constexpr (MODE == 3) ab[kf & 3][mt] = ald16<1>(ap[mt] + (kf + 4) * 64);
        else ab[kf & 3][mt] = lda2(kf + 4, mt);
      }
    }
  }
}

// ---------------- barriers: relaxed counters (r10-proven) ----------------

__device__ __forceinline__ void sbar(unsigned* sc, unsigned n){
  __syncthreads();                               // staging stores L2-acked
  if (threadIdx.x == 0){
    add_u(sc, 1u);
    while (ld_u(sc) < n) __builtin_amdgcn_s_sleep(1);
    asm volatile("" ::: "memory");
  }
  __syncthreads();
}

__device__ __forceinline__ void gbar(unsigned* arr, unsigned* gc, int sub, int it){
  __syncthreads();
  if (threadIdx.x == 0){
    add_u(arr, 1u);
    if (sub == 0){
      while (ld_u(arr) < 32u * (unsigned)(it + 1)) __builtin_amdgcn_s_sleep(1);
      add_u(gc, 1u);
    }
    while (ld_u(gc) < 8u * (unsigned)(it + 1)) __builtin_amdgcn_s_sleep(1);
    asm volatile("" ::: "memory");
  }
  __syncthreads();
}

// ---------------- 4-role persistent pipeline, XCD-censused staging ----------------
// groups: g0=ih0(32) g1,2=hh0(64) g3,4=ih1(64) g5,6=hh1(64) g7=idle(32)
// iter i: G0: P0_i = emb[tok_i]@Wih0+b0 ; G1: h0_{i-1} = tanh(P0 + h0_{i-2}@Whh0)
//         G2: P1_{i-2} = h0_{i-2}@Wih1+b1 ; G3: h1_{i-3} = tanh(P1 + h1_{i-4}@Whh1)
// coop: per-group (=XCD) stage of A panel via ONE sc1 pass -> local L2 -> sc0 bulk.
// !coop fallback: exact r10 path (sc1 from originals).

__global__ __launch_bounds__(512, 2) void rnn4(
    const float* __restrict__ emb,
    const int* __restrict__ tokens,
    const unsigned short* __restrict__ Wih0T,  // [2048][1024] fp16
    const unsigned short* __restrict__ Whh0T,  // [2048][2048]
    const unsigned short* __restrict__ Wih1T,  // [2048][2048]
    const unsigned short* __restrict__ Whh1T,  // [2048][2048]
    const float* __restrict__ b0,
    const float* __restrict__ b1,
    unsigned short* __restrict__ h0,    // [2][BH] zeroed
    unsigned short* __restrict__ h1,    // [2][BH] zeroed
    unsigned short* __restrict__ P0,    // [2][BH]
    unsigned short* __restrict__ P1a,   // [2][BH]
    unsigned short* __restrict__ P1b,   // [2][BH]
    unsigned short* __restrict__ stg,   // [8][BH] per-group staging
    const int* __restrict__ lengths,
    unsigned* __restrict__ zp)          // zeroed control page
{
  extern __shared__ char lds[];
  char* Wl = lds;
  char* zone = lds + 131072;            // 24 KB: partials, then f32 s-tile
  __shared__ int s_grp, s_sub, s_coop;

  const int tid = threadIdx.x, l = tid & 63, w = tid >> 6;
  const int mw = w & 1, kw = w >> 1;
  const int fr = l & 15, q = l >> 4;

  // ---- census + claim + spill repair (r5-proven machinery) ----
  if (tid == 0){
    unsigned x;
    asm volatile("s_getreg_b32 %0, hwreg(HW_REG_XCC_ID)" : "=s"(x));
    x &= 7u;
    unsigned mysub = add_u(&zp[x], 1u);
    add_u(&zp[33], 1u);
    while (ld_u(&zp[33]) < 256u) __builtin_amdgcn_s_sleep(1);
    unsigned cnt[8]; int coop = 1;
    #pragma unroll
    for (int i = 0; i < 8; ++i){ cnt[i] = ld_u(&zp[i]); if (cnt[i] != 32u) coop = 0; }
    int g = (int)x, s = (int)mysub;
    if (mysub >= 32u){
      unsigned j = add_u(&zp[34], 1u);
      for (int xx = 0; xx < 8; ++xx){
        unsigned have = (cnt[xx] < 32u) ? (32u - cnt[xx]) : 0u;
        if (j < have){ g = xx; s = (int)(cnt[xx] + j); break; }
        j -= have;
      }
    }
    s_grp = g; s_sub = s; s_coop = coop;
  }
  __syncthreads();
  const int grp = s_grp, sub = s_sub;
  const bool coop = (s_coop != 0);
  unsigned* gc   = zp + 32;
  unsigned* arr  = zp + 256 + grp * 64;
  unsigned* sctr = zp + 256 + grp * 64 + 32;

  int role = -1, tile = 0;
  if (grp == 0){ role = 0; tile = sub; }
  else if (grp <= 2){ role = 1; tile = (grp - 1) * 32 + sub; }
  else if (grp <= 4){ role = 2; tile = (grp - 3) * 32 + sub; }
  else if (grp <= 6){ role = 3; tile = (grp - 5) * 32 + sub; }

  const int kh = (role == 2) ? (tile & 1) : 0;
  const int c0 = (role == 0) ? tile * 64 : (role == 2) ? (tile >> 1) * 64 : tile * 32;

  // ---- W slice into swizzled LDS (once) ----
  if (role >= 0){
    const unsigned short* src; int NC, KC, srcK, kofs;
    if (role == 0){ src = Wih0T; NC = 64; KC = 1024; srcK = 1024; kofs = 0; }
    else if (role == 2){ src = Wih1T; NC = 64; KC = 1024; srcK = 2048; kofs = kh * 1024; }
    else { src = (role == 1) ? Whh0T : Whh1T; NC = 32; KC = 2048; srcK = 2048; kofs = 0; }
    int nch = NC * (KC / 8);
    for (int i2 = tid; i2 < nch; i2 += 512){
      int c = i2 / (KC / 8), kg = i2 % (KC / 8);
      uint4 v = *(const uint4*)(src + (size_t)(c0 + c) * srcK + kofs + kg * 8);
      int byte = (c * KC + kg * 8) * 2 ^ ((c & 31) << 4);
      *(uint4*)(Wl + byte) = v;
    }
  }
  __syncthreads();

  bool w64 = false;
  if (grp == 0) w64 = ((tokens[1] | tokens[3] | tokens[5] | tokens[7]) == 0);

  // finish-pass constants (row-contiguous mapping; static per thread)
  const int rIP = tid >> 3;                       // 0..63 row-in-phase
  float bias8[8] = {0,0,0,0,0,0,0,0};
  if (role == 0){
    #pragma unroll
    for (int j = 0; j < 8; ++j) bias8[j] = b0[c0 + (tid & 7) * 8 + j];
  } else if (role == 2 && kh == 0){
    #pragma unroll
    for (int j = 0; j < 8; ++j) bias8[j] = b1[c0 + (tid & 7) * 8 + j];
  }
  int lenRow[2] = {0, 0};
  float hpz[2][4] = {{0,0,0,0},{0,0,0,0}};
  if (role == 1 || role == 3){
    lenRow[0] = lengths[rIP];
    lenRow[1] = lengths[64 + rIP];
  }

  unsigned stct = 0;
  for (int it = 0; it < 515; ++it){
    const unsigned short* stga = nullptr;

    // ---- staging (coop only): one sc1 pass -> local L2 ----
    if (coop){
      if (grp == 0){
        if (it <= 511){
          unsigned short* sd = stg;               // [128][1024] fp16
          int gt = sub * 512 + tid;               // 0..16383
          int row = gt >> 7;
          int c8 = (gt & 127) * 8;
          long tix = (long)row * Tq + it;
          int tok = w64 ? tokens[2 * tix] : tokens[tix];
          const float* sf = emb + (size_t)tok * Dq + c8;
          float4 f0 = *(const float4*)sf;
          float4 f1 = *(const float4*)(sf + 4);
          h8 hv;
          hv[0] = (_Float16)f0.x; hv[1] = (_Float16)f0.y; hv[2] = (_Float16)f0.z; hv[3] = (_Float16)f0.w;
          hv[4] = (_Float16)f1.x; hv[5] = (_Float16)f1.y; hv[6] = (_Float16)f1.z; hv[7] = (_Float16)f1.w;
          *(h8*)(sd + row * 1024 + c8) = hv;      // plain store -> local L2
          ++stct;
          sbar(sctr, 32u * stct);
          stga = sd;
        }
      } else if (grp <= 6){
        const int lo = (grp <= 2) ? 1 : (grp <= 4) ? 2 : 3;
        if (it >= lo && it <= lo + 511){
          const unsigned short* hsrc = ((grp <= 4) ? h0 : h1) + (it & 1) * BH;
          unsigned short* sd = stg + (size_t)grp * BH;
          int gt = sub * 512 + tid;
          const char* sb = (const char*)hsrc;
          char* db = (char*)sd;
          h8 v0 = ald16<2>(sb + (size_t)gt * 32);
          h8 v1 = ald16<2>(sb + (size_t)gt * 32 + 16);
          vwait<0>();
          *(h8*)(db + (size_t)gt * 32) = v0;
          *(h8*)(db + (size_t)gt * 32 + 16) = v1;
          ++stct;
          sbar(sctr, 32u * stct);
          stga = sd;
        }
      }
    }

    // ---- compute ----
    if (role == 0 || role == 2){
      // ======== ih: MT=4 NT=4 KF=8, KC=1024 ========
      const int t = (role == 0) ? it : it - 2;
      if (t >= 0 && t <= 511){
        int bb[4], swz[4];
        #pragma unroll
        for (int nt = 0; nt < 4; ++nt){
          int cl = nt * 16 + fr;
          bb[nt] = (cl * 1024 + kw * 256 + q * 8) * 2;
          swz[nt] = (cl & 31) << 4;
        }
        const char* ap[4];
        f4 acc[4][4] = {};
        if (role == 0){
          if (coop){
            #pragma unroll
            for (int mt = 0; mt < 4; ++mt){
              int row = mw * 64 + mt * 16 + fr;
              ap[mt] = (const char*)(stga + (size_t)row * 1024 + kw * 256 + q * 8);
            }
            mmX<4, 4, 8, 3>(acc, ap, Wl, bb, swz);
          } else {
            #pragma unroll
            for (int mt = 0; mt < 4; ++mt){
              int row = mw * 64 + mt * 16 + fr;
              long idx = (long)row * Tq + t;
              int tok = w64 ? tokens[2 * idx] : tokens[idx];
              ap[mt] = (const char*)(emb + (size_t)tok * Dq) + kw * 1024 + q * 32;
            }
            mmX<4, 4, 8, 2>(acc, ap, Wl, bb, swz);
          }
        } else {
          const unsigned short* asrc = coop ? stga : (h0 + (it & 1) * BH);
          #pragma unroll
          for (int mt = 0; mt < 4; ++mt){
            int row = mw * 64 + mt * 16 + fr;
            ap[mt] = (const char*)(asrc + (size_t)row * Hq + kh * 1024 + kw * 256 + q * 8);
          }
          if (coop) mmX<4, 4, 8, 3>(acc, ap, Wl, bb, swz);
          else      mmX<4, 4, 8, 1>(acc, ap, Wl, bb, swz);
        }

        unsigned short* dst = ((role == 0) ? P0 : (kh == 0 ? P1a : P1b)) + (t & 1) * BH;
        #pragma unroll
        for (int mwr = 0; mwr < 2; ++mwr){
          __syncthreads();                        // S1: zone free
          if (mw == mwr && kw > 0){
            #pragma unroll
            for (int mt = 0; mt < 4; ++mt)
              #pragma unroll
              for (int nt = 0; nt < 4; ++nt){
                ushort4 u = { f2h(acc[mt][nt][0]), f2h(acc[mt][nt][1]),
                              f2h(acc[mt][nt][2]), f2h(acc[mt][nt][3]) };
                *(ushort4*)(zone + (kw - 1) * 8192 + (mt * 4 + nt) * 512 + l * 8) = u;
              }
          }
          __syncthreads();                        // S2
          if (mw == mwr && kw == 0){
            #pragma unroll
            for (int mt = 0; mt < 4; ++mt)
              #pragma unroll
              for (int nt = 0; nt < 4; ++nt){
                #pragma unroll
                for (int j = 0; j < 3; ++j){
                  ushort4 u = *(ushort4*)(zone + j * 8192 + (mt * 4 + nt) * 512 + l * 8);
                  acc[mt][nt][0] += h2f(u.x); acc[mt][nt][1] += h2f(u.y);
                  acc[mt][nt][2] += h2f(u.z); acc[mt][nt][3] += h2f(u.w);
                }
              }
          }
          __syncthreads();                        // S3: partial reads done
          if (mw == mwr && kw == 0){
            float* szw = (float*)zone;            // [64][64] f32
            #pragma unroll
            for (int mt = 0; mt < 4; ++mt)
              #pragma unroll
              for (int nt = 0; nt < 4; ++nt)
                #pragma unroll
                for (int r = 0; r < 4; ++r)
                  szw[(mt * 16 + q * 4 + r) * 64 + nt * 16 + fr] = acc[mt][nt][r];
          }
          __syncthreads();                        // S4
          {                                       // finish: all 512 threads
            const float* sz = (const float*)zone;
            int cL = (tid & 7) * 8;
            float v[8];
            #pragma unroll
            for (int j = 0; j < 8; ++j) v[j] = sz[rIP * 64 + cL + j] + bias8[j];
            size_t o = (size_t)(mwr * 64 + rIP) * Hq + (c0 + cL);
            st_q((ull*)(dst + o),     pack4h(v[0], v[1], v[2], v[3]));
            st_q((ull*)(dst + o) + 1, pack4h(v[4], v[5], v[6], v[7]));
          }
        }
      }
    } else if (role == 1 || role == 3){
      // ======== hh: MT=4 NT=2 KF=16, KC=2048 ========
      const int t = (role == 1) ? it - 1 : it - 3;
      if (t >= 0 && t <= 511){
        int bb[2], swz[2];
        #pragma unroll
        for (int nt = 0; nt < 2; ++nt){
          int cl = nt * 16 + fr;
          bb[nt] = (cl * 2048 + kw * 512 + q * 8) * 2;
          swz[nt] = (cl & 31) << 4;
        }
        unsigned short* hbuf = (role == 1) ? h0 : h1;
        const unsigned short* asrc = coop ? stga : (hbuf + (it & 1) * BH);
        const char* ap[4];
        #pragma unroll
        for (int mt = 0; mt < 4; ++mt){
          int row = mw * 64 + mt * 16 + fr;
          ap[mt] = (const char*)(asrc + (size_t)row * Hq + kw * 512 + q * 8);
        }
        f4 acc[4][2] = {};
        if (coop) mmX<4, 2, 16, 3>(acc, ap, Wl, bb, swz);
        else      mmX<4, 2, 16, 1>(acc, ap, Wl, bb, swz);

        const unsigned short* Pa = ((role == 1) ? P0 : P1a) + (t & 1) * BH;
        const unsigned short* Pb = (role == 3) ? (P1b + (t & 1) * BH) : nullptr;
        unsigned short* hdst = hbuf + (t & 1) * BH;
        #pragma unroll
        for (int mwr = 0; mwr < 2; ++mwr){
          __syncthreads();                        // S1
          if (mw == mwr && kw > 0){
            #pragma unroll
            for (int mt = 0; mt < 4; ++mt)
              #pragma unroll
              for (int nt = 0; nt < 2; ++nt){
                ushort4 u = { f2h(acc[mt][nt][0]), f2h(acc[mt][nt][1]),
                              f2h(acc[mt][nt][2]), f2h(acc[mt][nt][3]) };
                *(ushort4*)(zone + (kw - 1) * 8192 + (mt * 2 + nt) * 512 + l * 8) = u;
              }
          }
          __syncthreads();                        // S2
          if (mw == mwr && kw == 0){
            #pragma unroll
            for (int mt = 0; mt < 4; ++mt)
              #pragma unroll
              for (int nt = 0; nt < 2; ++nt){
                #pragma unroll
                for (int j = 0; j < 3; ++j){
                  ushort4 u = *(ushort4*)(zone + j * 8192 + (mt * 2 + nt) * 512 + l * 8);
                  acc[mt][nt][0] += h2f(u.x); acc[mt][nt][1] += h2f(u.y);
                  acc[mt][nt][2] += h2f(u.z); acc[mt][nt][3] += h2f(u.w);
                }
              }
          }
          __syncthreads();                        // S3
          if (mw == mwr && kw == 0){
            float* szw = (float*)zone;            // [64][32] f32
            #pragma unroll
            for (int mt = 0; mt < 4; ++mt)
              #pragma unroll
              for (int nt = 0; nt < 2; ++nt)
                #pragma unroll
                for (int r = 0; r < 4; ++r)
                  szw[(mt * 16 + q * 4 + r) * 32 + nt * 16 + fr] = acc[mt][nt][r];
          }
          __syncthreads();                        // S4
          {                                       // finish: all 512 threads
            const float* sz = (const float*)zone;
            int cL = (tid & 7) * 4;
            size_t o = (size_t)(mwr * 64 + rIP) * Hq + (c0 + cL);
            float v[4];
            #pragma unroll
            for (int j = 0; j < 4; ++j) v[j] = sz[rIP * 32 + cL + j];
            ull pa = ld_q((const ull*)(Pa + o));
            #pragma unroll
            for (int j = 0; j < 4; ++j) v[j] += h2f((unsigned short)(pa >> (16 * j)));
            if (role == 3){
              ull pb = ld_q((const ull*)(Pb + o));
              #pragma unroll
              for (int j = 0; j < 4; ++j) v[j] += h2f((unsigned short)(pb >> (16 * j)));
            }
            const int len = lenRow[mwr];
            float ho[4];
            #pragma unroll
            for (int j = 0; j < 4; ++j){
              float hn = fast_tanh(v[j]);
              float x = (t < len) ? hn : hpz[mwr][j];
              hpz[mwr][j] = x;
              ho[j] = x;
            }
            st_q((ull*)(hdst + o), pack4h(ho[0], ho[1], ho[2], ho[3]));
          }
        }
      }
    }
    if (it < 514) gbar(arr, gc, sub, it);
  }
}

// ---------------- launch ----------------

extern "C" void kernel_launch(void* const* d_in, const int* in_sizes, int n_in,
                              void* d_out, int out_size, void* d_ws, size_t ws_size,
                              hipStream_t stream)
{
  (void)in_sizes; (void)n_in; (void)out_size; (void)ws_size;
  const int*   tokens  = (const int*)d_in[0];
  const int*   lengths = (const int*)d_in[1];
  const float* emb     = (const float*)d_in[2];
  const float* Wih0    = (const float*)d_in[3];
  const float* Whh0    = (const float*)d_in[4];
  const float* b0      = (const float*)d_in[5];
  const float* Wih1    = (const float*)d_in[6];
  const float* Whh1    = (const float*)d_in[7];
  const float* b1      = (const float*)d_in[8];

  char* ws = (char*)d_ws;
  size_t off = 0;
  auto alloc = [&](size_t bytes)->char*{
    char* p = ws + off; off += (bytes + 255) & ~(size_t)255; return p;
  };
  unsigned short* WTih0 = (unsigned short*)alloc((size_t)Hq * Dq * 2);   //  4 MB
  unsigned short* WThh0 = (unsigned short*)alloc((size_t)Hq * Hq * 2);   //  8 MB
  unsigned short* WTih1 = (unsigned short*)alloc((size_t)Hq * Hq * 2);   //  8 MB
  unsigned short* WThh1 = (unsigned short*)alloc((size_t)Hq * Hq * 2);   //  8 MB
  unsigned short* h0b   = (unsigned short*)alloc((size_t)2 * BH * 2);
  unsigned short* h1b   = (unsigned short*)alloc((size_t)2 * BH * 2);
  unsigned short* P0b   = (unsigned short*)alloc((size_t)2 * BH * 2);
  unsigned short* P1ab  = (unsigned short*)alloc((size_t)2 * BH * 2);
  unsigned short* P1bb  = (unsigned short*)alloc((size_t)2 * BH * 2);
  unsigned short* stgb  = (unsigned short*)alloc((size_t)8 * BH * 2);    //  4 MB
  unsigned*       zp    = (unsigned*)alloc(4096);
  // total ~38 MB (r5 proved this size launches fine)

  transpose_cast<<<dim3(Hq / 32, Dq / 32), dim3(32, 8), 0, stream>>>(Wih0, WTih0, Dq, Hq);
  transpose_cast<<<dim3(Hq / 32, Hq / 32), dim3(32, 8), 0, stream>>>(Whh0, WThh0, Hq, Hq);
  transpose_cast<<<dim3(Hq / 32, Hq / 32), dim3(32, 8), 0, stream>>>(Wih1, WTih1, Hq, Hq);
  transpose_cast<<<dim3(Hq / 32, Hq / 32), dim3(32, 8), 0, stream>>>(Whh1, WThh1, Hq, Hq);

  hipMemsetAsync(h0b, 0, (size_t)2 * BH * 2, stream);
  hipMemsetAsync(h1b, 0, (size_t)2 * BH * 2, stream);
  hipMemsetAsync(zp, 0, 4096, stream);

  hipFuncSetAttribute((const void*)rnn4, hipFuncAttributeMaxDynamicSharedMemorySize, 155648);
  rnn4<<<256, 512, 155648, stream>>>(emb, tokens, WTih0, WThh0, WTih1, WThh1,
                                     b0, b1, h0b, h1b, P0b, P1ab, P1bb, stgb,
                                     lengths, zp);

  h2f_out<<<(BH + 255) / 256, 256, 0, stream>>>(h1b + BH, (float*)d_out, BH);
}